// Round 1
// 295.211 us; speedup vs baseline: 1.0357x; 1.0357x over previous
//
#include <hip/hip_runtime.h>
#include <math.h>

#define T_LEN 4096
#define B_SZ  512

// emission: fl(fl(fl(-0.5*x)*x) - fl32(0.5*log(2*pi)))
__device__ __forceinline__ float emis(float xv) {
    float a = __fmul_rn(-0.5f, xv);
    float b = __fmul_rn(a, xv);
    return __fsub_rn(b, (float)0.9189385332046727);
}

// ---------------------------------------------------------------------------
#define DPP_ROR0(K, SRC) __builtin_amdgcn_update_dpp(0, (SRC), 0x120 + (K), 0xF, 0xF, false)
#define M3(x, y, z) fmaxf(fmaxf(x, y), z)

#define ADDPP(DST, K)                                                                 \
    asm("v_add_f32_dpp %0, %1, %2 row_ror:" #K " row_mask:0xf bank_mask:0xf"          \
        : "=v"(DST) : "v"(d), "v"(a[K]))

#define STEPC(ET)                                                                     \
    {                                                                                 \
        float s0 = __fadd_rn(d, a[0]);                                                \
        float s1, s2, s3, s4, s5, s6, s7, s8, s9, s10, s11, s12, s13, s14, s15;       \
        ADDPP(s1, 1);   ADDPP(s2, 2);   ADDPP(s3, 3);   ADDPP(s4, 4);                 \
        ADDPP(s5, 5);   ADDPP(s6, 6);   ADDPP(s7, 7);   ADDPP(s8, 8);                 \
        ADDPP(s9, 9);   ADDPP(s10, 10); ADDPP(s11, 11); ADDPP(s12, 12);               \
        ADDPP(s13, 13); ADDPP(s14, 14); ADDPP(s15, 15);                               \
        float u0 = M3(s0, s1, s2),  u1 = M3(s3, s4, s5),  u2 = M3(s6, s7, s8);        \
        float u3 = M3(s9, s10, s11), u4 = M3(s12, s13, s14);                          \
        float m = fmaxf(M3(u0, u1, u2), M3(u3, u4, s15));                             \
        d = __fadd_rn(m, ET);                                                         \
    }

#define GRP4(QV, SLOTDW)                                                              \
    {                                                                                 \
        float4 dq;                                                                    \
        STEPC(QV.x) dq.x = d; STEPC(QV.y) dq.y = d;                                   \
        STEPC(QV.z) dq.z = d; STEPC(QV.w) dq.w = d;                                   \
        *(float4*)(db + (SLOTDW)) = dq;                                               \
    }

// Byte map application via v_perm — used for boundary chain.
#define PERMSEL(V, Q)                                                                 \
    {                                                                                 \
        int sel_ = (V) & 7;                                                           \
        int lo_, hi_;                                                                 \
        asm("v_perm_b32 %0, %1, %2, %3" : "=v"(lo_) : "v"((Q).y), "v"((Q).x), "v"(sel_)); \
        asm("v_perm_b32 %0, %1, %2, %3" : "=v"(hi_) : "v"((Q).w), "v"((Q).z), "v"(sel_)); \
        V = (((V) & 8) ? hi_ : lo_) & 0xff;                                           \
    }

#define WALK64(BASE, CUR, PRE, POST)                                                  \
    {                                                                                 \
        uint4 m_[8];                                                                  \
        _Pragma("unroll") for (int z_ = 0; z_ < 8; ++z_)                              \
            m_[z_] = *(const uint4*)((BASE) + (63 - z_) * 16);                        \
        for (int r_ = 63; r_ >= 15; r_ -= 8) {                                        \
            uint4 n_[8];                                                              \
            _Pragma("unroll") for (int z_ = 0; z_ < 8; ++z_)                          \
                n_[z_] = *(const uint4*)((BASE) + (r_ - 8 - z_) * 16);                \
            _Pragma("unroll") for (int z_ = 0; z_ < 8; ++z_) {                        \
                PRE(r_ - z_, CUR) PERMSEL(CUR, m_[z_]) POST(r_ - z_, CUR)             \
            }                                                                         \
            _Pragma("unroll") for (int z_ = 0; z_ < 8; ++z_) m_[z_] = n_[z_];         \
        }                                                                             \
        _Pragma("unroll") for (int z_ = 0; z_ < 8; ++z_) {                            \
            PRE(7 - z_, CUR) PERMSEL(CUR, m_[z_]) POST(7 - z_, CUR)                   \
        }                                                                             \
    }

// Nibble-packed map application: row = u64 of 16 nibbles, next = (row>>4*cur)&15.
#define NIBHOP(V, Q) (V) = (int)(((Q) >> ((unsigned)(V) << 2)) & 15ull);

#define NWALK64(BASE, CUR, POST)                                                      \
    {                                                                                 \
        const unsigned long long* bb_ = (BASE);                                       \
        unsigned long long m_[8];                                                     \
        _Pragma("unroll") for (int z_ = 0; z_ < 8; ++z_) m_[z_] = bb_[63 - z_];       \
        for (int r_ = 63; r_ >= 15; r_ -= 8) {                                       \
            unsigned long long n_[8];                                                 \
            _Pragma("unroll") for (int z_ = 0; z_ < 8; ++z_) n_[z_] = bb_[r_ - 8 - z_]; \
            _Pragma("unroll") for (int z_ = 0; z_ < 8; ++z_) {                        \
                NIBHOP(CUR, m_[z_]) POST(r_ - z_, CUR)                                \
            }                                                                         \
            _Pragma("unroll") for (int z_ = 0; z_ < 8; ++z_) m_[z_] = n_[z_];         \
        }                                                                             \
        _Pragma("unroll") for (int z_ = 0; z_ < 8; ++z_) {                            \
            NIBHOP(CUR, m_[z_]) POST(7 - z_, CUR)                                     \
        }                                                                             \
    }

#define NOPX(r, c)
#define EBL_PRE(r, c) eb[r] = (unsigned char)(c);
#define OUT_POST(r, c) ob[r] = (c);

// ---------------------------------------------------------------------------
// Single fused kernel. 2 batches/block, 4 waves.
// Prologue (all threads): logA/logAT into LDS (bit-exact: pairwise-16 rowsum,
// fp64 log) + emission chunks 0,1 into the Ebuf ring.
// Wave 0 (g<2): Viterbi chains; reads E from LDS ring, writes delta dbuf.
// Waves 1,2: psi of chunk p-1 from dbuf -> nibble-packed pnib (logAT from LDS,
//            1-deep pipelined column prefetch).
// Wave 3: emissions for chunk p+2 into Ebuf ring (lanes 0-63) + nibble
//         map-walk of chunk p-2 -> Ml (lanes 0-31).
// Tail: argmax + boundary chain + 128 chunk walks writing out.
// Zero intermediate global traffic; no second kernel.
__global__ __launch_bounds__(256) void k_fused(const float* __restrict__ x,
                                               const float* __restrict__ hmm,
                                               int* __restrict__ out) {
    __shared__ __align__(16) float dbuf[2][2][16][68];   // 17408 B
    __shared__ unsigned long long pnib[2][64 * 65];      // 66560 B
    __shared__ uint4 Mlv[2][64];                         // 2048 B
    __shared__ unsigned char Ebl[2][64];                 // 128 B
    __shared__ float carry_l[2][16];                     // 128 B
    __shared__ float logA_l[256];                        // 1024 B
    __shared__ __align__(16) float logAT_l[272];         // 1088 B (+16 pad row for pipeline over-read)
    __shared__ __align__(16) float Ebuf[4][2][64];       // 2048 B (4-deep ring, 2 groups)

    const int tid = threadIdx.x;
    const int wave = tid >> 6;
    const int blk = blockIdx.x;

    // ---- prologue: logA/logAT (exact replica of the old k_emit block 0) ----
    {
        const int i = tid >> 4, j = tid & 15;
        const float* row = hmm + i * 16;
        float r[8];
#pragma unroll
        for (int k = 0; k < 8; ++k) r[k] = __fadd_rn(row[k], row[k + 8]);
        float s = __fadd_rn(
            __fadd_rn(__fadd_rn(r[0], r[1]), __fadd_rn(r[2], r[3])),
            __fadd_rn(__fadd_rn(r[4], r[5]), __fadd_rn(r[6], r[7])));
        float la = (float)log((double)row[j]);
        float ls = (float)log((double)s);
        float v = __fsub_rn(la, ls);
        logA_l[tid] = v;
        logAT_l[j * 16 + i] = v;
        if (tid < 16) logAT_l[256 + tid] = 0.f;
        // emission chunks 0 and 1 into the ring (256 threads = 2 chunks x 2 groups x 64)
        const int cc0 = tid >> 7, gp = (tid >> 6) & 1, l0 = tid & 63;
        Ebuf[cc0][gp][l0] = emis(x[(size_t)(blk * 2 + gp) * T_LEN + 64 * cc0 + l0 + 1]);
    }
    __syncthreads();

    if (wave == 0) {
        asm volatile("s_setprio 3");
        const int j = tid & 15, g = tid >> 4;  // active g<2
        float a[16];
        float d = 0.f;
        float4 q0, q1, q2, q3;
        if (g < 2) {
            const int b = blk * 2 + g;
            a[0] = logA_l[j * 16 + j];
#define LOADA(K) { int sk = DPP_ROR0(K, j); a[K] = logA_l[sk * 16 + j]; }
            LOADA(1)  LOADA(2)  LOADA(3)  LOADA(4)  LOADA(5)
            LOADA(6)  LOADA(7)  LOADA(8)  LOADA(9)  LOADA(10)
            LOADA(11) LOADA(12) LOADA(13) LOADA(14) LOADA(15)
#undef LOADA
            float e0 = emis(x[(size_t)b * T_LEN]);
            d = __fadd_rn(logA_l[j], e0);            // delta0
            const float4* e0p = (const float4*)&Ebuf[0][g][0];
            q0 = e0p[0]; q1 = e0p[1]; q2 = e0p[2]; q3 = e0p[3];
        }
        for (int p = 0; p < 66; ++p) {
            __syncthreads();
            if (p < 64 && g < 2) {
                float* db = &dbuf[p & 1][g][j][0];
                db[64] = d;                           // delta at t = 64p
                const float4* ecur = (const float4*)&Ebuf[p & 3][g][0];
                const float4* enxt = (const float4*)&Ebuf[(p + 1) & 3][g][0];
                if (p < 63) {
#pragma clang loop unroll(disable)
                    for (int ii = 0; ii < 3; ++ii) {
                        GRP4(q0, ii * 16 + 0)  q0 = ecur[(ii + 1) * 4 + 0];
                        GRP4(q1, ii * 16 + 4)  q1 = ecur[(ii + 1) * 4 + 1];
                        GRP4(q2, ii * 16 + 8)  q2 = ecur[(ii + 1) * 4 + 2];
                        GRP4(q3, ii * 16 + 12) q3 = ecur[(ii + 1) * 4 + 3];
                    }
                    // last quad of this chunk; prefetch first quad of chunk p+1
                    // (filled by wave 3 during phase p-1 -> barrier-ordered, no race)
                    GRP4(q0, 48) q0 = enxt[0];
                    GRP4(q1, 52) q1 = enxt[1];
                    GRP4(q2, 56) q2 = enxt[2];
                    GRP4(q3, 60) q3 = enxt[3];
                } else {
#pragma clang loop unroll(disable)
                    for (int ii = 0; ii < 3; ++ii) {
                        GRP4(q0, ii * 16 + 0)  q0 = ecur[(ii + 1) * 4 + 0];
                        GRP4(q1, ii * 16 + 4)  q1 = ecur[(ii + 1) * 4 + 1];
                        GRP4(q2, ii * 16 + 8)  q2 = ecur[(ii + 1) * 4 + 2];
                        GRP4(q3, ii * 16 + 12) q3 = ecur[(ii + 1) * 4 + 3];
                    }
                    GRP4(q0, 48) GRP4(q1, 52) GRP4(q2, 56)      // t=4081..4092
                    STEPC(q3.x) db[60] = d;                      // t=4093
                    STEPC(q3.y) db[61] = d;                      // t=4094
                    STEPC(q3.z) db[62] = d;                      // t=4095
                }
            }
        }
        if (g < 2) carry_l[g][j] = d;
    } else if (wave <= 2) {
        const int g2 = wave - 1;
        const int r = tid & 63;
        for (int p = 0; p < 66; ++p) {
            __syncthreads();
            const int c = p - 1;
            if (c >= 0 && c < 64) {
                const int t2 = 64 * c + 1 + r;
                if (t2 <= T_LEN - 1) {
                    const int q = c & 1;
                    const int rs = (r == 0) ? 64 : (r - 1);
                    float dd[16];
#pragma unroll
                    for (int i = 0; i < 16; ++i) dd[i] = dbuf[q][g2][i][rs];
                    unsigned long long pk = 0ull;
                    const float4* clp = (const float4*)&logAT_l[0];
                    float4 c0 = clp[0], c1 = clp[1], c2 = clp[2], c3 = clp[3];
#pragma clang loop unroll(disable)
                    for (int jj = 0; jj < 16; ++jj) {
                        // prefetch next column while reducing current (jj=15 reads pad row)
                        const float4* nxp = clp + ((jj + 1) << 2);
                        float4 n0 = nxp[0], n1 = nxp[1], n2 = nxp[2], n3 = nxp[3];
                        float best = __fadd_rn(dd[0], c0.x);
                        int arg = 0;
#define PSI1(IDX, COMP) { float s_ = __fadd_rn(dd[IDX], COMP); if (s_ > best) arg = IDX; best = fmaxf(best, s_); }
                        PSI1(1, c0.y)  PSI1(2, c0.z)  PSI1(3, c0.w)
                        PSI1(4, c1.x)  PSI1(5, c1.y)  PSI1(6, c1.z)  PSI1(7, c1.w)
                        PSI1(8, c2.x)  PSI1(9, c2.y)  PSI1(10, c2.z) PSI1(11, c2.w)
                        PSI1(12, c3.x) PSI1(13, c3.y) PSI1(14, c3.z) PSI1(15, c3.w)
#undef PSI1
                        pk |= (unsigned long long)arg << (jj * 4);
                        c0 = n0; c1 = n1; c2 = n2; c3 = n3;
                    }
                    pnib[g2][c * 65 + r] = pk;
                } else {  // c==63, r==63: t=4096 absent -> identity map
                    pnib[g2][c * 65 + 63] = 0xFEDCBA9876543210ull;
                }
            }
        }
    } else {
        const int l = tid - 192;
        const int g3 = l >> 4, z = l & 15;
        for (int p = 0; p < 66; ++p) {
            __syncthreads();
            // emissions for chunk p+2 into the ring (2 chunks ahead of wave 0's
            // main reads; 1 ahead of its end-of-chunk prefetch -> race-free)
            const int cc = p + 2;
            if (cc < 64) {
                const int t = 64 * cc + l + 1;
                if (t <= T_LEN - 1) {
                    Ebuf[cc & 3][0][l] = emis(x[(size_t)(blk * 2 + 0) * T_LEN + t]);
                    Ebuf[cc & 3][1][l] = emis(x[(size_t)(blk * 2 + 1) * T_LEN + t]);
                }
            }
            const int c = p - 2;
            if (c >= 0 && l < 32) {
                int cur = z;
                NWALK64(&pnib[g3][c * 65], cur, NOPX)
                ((unsigned char*)&Mlv[g3][c])[z] = (unsigned char)cur;
            }
        }
    }

    // ---- fused backtrace tail (all LDS-resident) ----
    __syncthreads();
    if (tid < 2) {
        const int g = tid;
        float best = carry_l[g][0]; int zT = 0;
#pragma unroll
        for (int i = 1; i < 16; ++i) {
            float s = carry_l[g][i];
            if (s > best) zT = i;
            best = fmaxf(best, s);
        }
        int z = zT;
        unsigned char* eb = &Ebl[g][0];
        WALK64((const unsigned char*)&Mlv[g][0], z, EBL_PRE, NOPX)
    }
    __syncthreads();
    if (tid < 128) {
        const int g = tid >> 6, c = tid & 63;
        int* ob = out + (size_t)(blk * 2 + g) * T_LEN + c * 64;
        int cur = Ebl[g][c];
        NWALK64(&pnib[g][c * 65], cur, OUT_POST)  // chunk63 identity hop writes out[4095]=zT
    }
}

// ---------------------------------------------------------------------------
extern "C" void kernel_launch(void* const* d_in, const int* in_sizes, int n_in,
                              void* d_out, int out_size, void* d_ws, size_t ws_size,
                              hipStream_t stream) {
    (void)in_sizes; (void)n_in; (void)out_size; (void)d_ws; (void)ws_size;
    const float* x   = (const float*)d_in[0];   // [512][4096] fp32
    const float* hmm = (const float*)d_in[1];   // [64][16][16] fp32 (only [0] used)
    int* out = (int*)d_out;                     // [512][4096] int32

    hipLaunchKernelGGL(k_fused, dim3(B_SZ / 2), dim3(256), 0, stream, x, hmm, out);
}